// Round 7
// baseline (182.861 us; speedup 1.0000x reference)
//
#include <hip/hip_runtime.h>
#include <cstdint>

// B=2, T=2048, C=1024, H=16, D=64 -> M = 4096.
// Inputs fp32 (dict order), OUTPUT FP32 (proven R7/R8). ws >= 64 MiB.
// Split order: k=[0,1024) q=[1024,2048) v=[2048,3072).
// ws layout (bf16): kqv 25.2MB | attn 8.4MB | xb 8.4MB | wkqvb 6.3MB | wprojb 2.1MB

typedef __bf16 bf16x8 __attribute__((ext_vector_type(8)));
typedef unsigned short u16x8 __attribute__((ext_vector_type(8)));
typedef float f32x4 __attribute__((ext_vector_type(4)));

__device__ __forceinline__ float bf2f(unsigned short u) {
    return __uint_as_float(((unsigned int)u) << 16);
}
__device__ __forceinline__ unsigned short f2bf(float f) {
    unsigned int u = __float_as_uint(f);
    u += 0x7fffu + ((u >> 16) & 1u);   // RNE
    return (unsigned short)(u >> 16);
}
__device__ __forceinline__ void stC(float* p, float v) { *p = v; }
__device__ __forceinline__ void stC(unsigned short* p, float v) { *p = f2bf(v); }

// async 16B global->LDS (DMA; LDS dest = wave-uniform base + lane*16)
__device__ __forceinline__ void gl2lds16(const unsigned short* g, unsigned short* l) {
    __builtin_amdgcn_global_load_lds(
        (__attribute__((address_space(1))) void*)g,
        (__attribute__((address_space(3))) void*)l, 16, 0, 0);
}

// XOR-swizzled LDS addressing for stride-64-short (128 B) rows:
// byte_off = row*128 + col*2, XOR'd with ((row&7)<<4).  Measured 0 conflicts
// for the 16-consecutive-rows fragment-read pattern (R1).
__device__ __forceinline__ unsigned short* swz(unsigned short* base, int row, int col) {
    const int off = ((row << 7) + (col << 1)) ^ ((row & 7) << 4);
    return (unsigned short*)((char*)base + off);
}
__device__ __forceinline__ const unsigned short* swz(const unsigned short* base, int row, int col) {
    const int off = ((row << 7) + (col << 1)) ^ ((row & 7) << 4);
    return (const unsigned short*)((const char*)base + off);
}

// ---------------------------------------------------------------------------
// fp32 -> bf16 bulk convert, three tensors in one launch
// ---------------------------------------------------------------------------
__device__ __forceinline__ void cvt8(const float* __restrict__ s, unsigned short* __restrict__ d) {
    const f32x4 a = *(const f32x4*)s;
    const f32x4 b = *(const f32x4*)(s + 4);
    u16x8 o;
    o[0] = f2bf(a[0]); o[1] = f2bf(a[1]); o[2] = f2bf(a[2]); o[3] = f2bf(a[3]);
    o[4] = f2bf(b[0]); o[5] = f2bf(b[1]); o[6] = f2bf(b[2]); o[7] = f2bf(b[3]);
    *(u16x8*)d = o;
}
__global__ __launch_bounds__(256) void cvt_bf16_3(
    const float* __restrict__ s0, unsigned short* __restrict__ d0, int n0,
    const float* __restrict__ s1, unsigned short* __restrict__ d1, int n1,
    const float* __restrict__ s2, unsigned short* __restrict__ d2, int n2)
{
    const int t = blockIdx.x * 256 + threadIdx.x;
    const int S = gridDim.x * 256;
    for (int i = t; i < n0 / 8; i += S) cvt8(s0 + (size_t)i * 8, d0 + (size_t)i * 8);
    for (int i = t; i < n1 / 8; i += S) cvt8(s1 + (size_t)i * 8, d1 + (size_t)i * 8);
    for (int i = t; i < n2 / 8; i += S) cvt8(s2 + (size_t)i * 8, d2 + (size_t)i * 8);
}

// ---------------------------------------------------------------------------
// gemm_qkv v2: 8-phase 256x256 schedule (T3+T4 template, plain HIP).
//  - BM=BN=256, BK=64, 8 waves (512 thr), wave grid 2M x 4N, per-wave C 128x64.
//  - LDS 128 KiB: As[2][256x64] + Bs[2][256x64] bf16, session-proven
//    (row&7)<<4 XOR swizzle via pre-swizzled global source + swz() reads.
//  - Per K-tile: 4 phases; phase = {ds_reads, 1-2 half-tile gl2lds stage,
//    barrier, lgkmcnt(0)+sched_barrier, 16 MFMA, barrier}.  B-frags read once
//    per tile (phase 0, 12 ds_reads), held in regs.
//  - Staggered staging (race-free by phase-barrier analysis):
//      tile t phases stage {A0(t+1)} {A1(t+1), B0(t+2)} {B1(t+2)} {}.
//    A(t+1) -> opposite buffer (tile t-1's reads done).  B(t+2) -> CURRENT
//    buffer's B region, read only in phase 0 (drained before phase-1 issue).
//  - Counted vmcnt: vmcnt(4) at phase 3 (2 half-tiles in flight), vmcnt(0)
//    only before the last tile.  Never a full drain in steady state.
// ---------------------------------------------------------------------------
template <int P>
__device__ __forceinline__ void mfmaq(f32x4 (&acc)[8][4],
                                      const bf16x8 (&af)[2][2],
                                      const bf16x8 (&bfr)[4][2]) {
#pragma unroll
    for (int m2 = 0; m2 < 2; m2++)
#pragma unroll
        for (int nt = 0; nt < 4; nt++)
#pragma unroll
            for (int ks = 0; ks < 2; ks++)
                acc[2 * P + m2][nt] = __builtin_amdgcn_mfma_f32_16x16x32_bf16(
                    af[m2][ks], bfr[nt][ks], acc[2 * P + m2][nt], 0, 0, 0);
}

__global__ __launch_bounds__(512) void gemm_qkv(
    const unsigned short* __restrict__ A, const unsigned short* __restrict__ B,
    unsigned short* __restrict__ C, int M, int N, int K)
{
    __shared__ __align__(16) unsigned short As[2][256 * 64];
    __shared__ __align__(16) unsigned short Bs[2][256 * 64];

    const int tid = threadIdx.x;
    const int bn = blockIdx.x, bm = blockIdx.y;
    const int w = tid >> 6, lane = tid & 63;
    const int quad = lane >> 4, l16 = lane & 15;
    const int wm = (w >> 2) * 128, wn = (w & 3) * 64;
    const int NT = K >> 6;                      // 16 K-tiles

    f32x4 acc[8][4] = {};

    const int srow8 = lane >> 3;                // 0..7 within 8-row group
    const int scol = ((lane & 7) ^ srow8) * 8;  // inverse-swizzled source col
    const unsigned short* Ab = A + (size_t)bm * 256 * K;
    const unsigned short* Bb = B + (size_t)bn * 256 * K;

    // stage half hh (128 rows) of K-tile tT for matrix G into lds buffer
    auto stage = [&](const unsigned short* __restrict__ G, unsigned short* lds,
                     int tT, int hh) {
#pragma unroll
        for (int i = 0; i < 2; i++) {
            const int r = hh * 128 + w * 16 + i * 8;      // wave-uniform
            gl2lds16(G + (size_t)(r + srow8) * K + tT * 64 + scol, lds + r * 64);
        }
    };
    auto ldA = [&](bf16x8 (&af)[2][2], const unsigned short* AsB, int p) {
#pragma unroll
        for (int m2 = 0; m2 < 2; m2++)
#pragma unroll
            for (int ks = 0; ks < 2; ks++)
                af[m2][ks] = *(const bf16x8*)swz(AsB, wm + p * 32 + m2 * 16 + l16,
                                                 ks * 32 + quad * 8);
    };
    auto ldB = [&](bf16x8 (&bf_)[4][2], const unsigned short* BsB) {
#pragma unroll
        for (int nt = 0; nt < 4; nt++)
#pragma unroll
            for (int ks = 0; ks < 2; ks++)
                bf_[nt][ks] = *(const bf16x8*)swz(BsB, wn + nt * 16 + l16,
                                                  ks * 32 + quad * 8);
    };

    // ---- prologue: B(0), A(0), B(1); wait tile-0 resident (B(1) in flight) ----
    stage(Bb, Bs[0], 0, 0); stage(Bb, Bs[0], 0, 1);
    stage(Ab, As[0], 0, 0); stage(Ab, As[0], 0, 1);
    stage(Bb, Bs[1], 1, 0); stage(Bb, Bs[1], 1, 1);
    asm volatile("s_waitcnt vmcnt(4)" ::: "memory");
    __builtin_amdgcn_s_barrier();

    for (int t = 0; t < NT; t++) {
        const unsigned short* AsB = As[t & 1];
        const unsigned short* BsB = Bs[t & 1];
        unsigned short* AsN = As[(t + 1) & 1];
        unsigned short* BsN = Bs[t & 1];        // (t+2)&1 == t&1
        bf16x8 bfr[4][2];
        // ---- phase 0: 12 ds_reads (A q0 + all B), stage A0(t+1) ----
        {
            bf16x8 af[2][2];
            ldA(af, AsB, 0);
            ldB(bfr, BsB);
            if (t + 1 < NT) stage(Ab, AsN, t + 1, 0);
            __builtin_amdgcn_s_barrier();
            asm volatile("s_waitcnt lgkmcnt(0)" ::: "memory");
            __builtin_amdgcn_sched_barrier(0);
            mfmaq<0>(acc, af, bfr);
            __builtin_amdgcn_s_barrier();
        }
        // ---- phase 1: A q1, stage A1(t+1) + B0(t+2) ----
        {
            bf16x8 af[2][2];
            ldA(af, AsB, 1);
            if (t + 1 < NT) stage(Ab, AsN, t + 1, 1);
            if (t + 2 < NT) stage(Bb, BsN, t + 2, 0);
            __builtin_amdgcn_s_barrier();
            asm volatile("s_waitcnt lgkmcnt(0)" ::: "memory");
            __builtin_amdgcn_sched_barrier(0);
            mfmaq<1>(acc, af, bfr);
            __builtin_amdgcn_s_barrier();
        }
        // ---- phase 2: A q2, stage B1(t+2) ----
        {
            bf16x8 af[2][2];
            ldA(af, AsB, 2);
            if (t + 2 < NT) stage(Bb, BsN, t + 2, 1);
            __builtin_amdgcn_s_barrier();
            asm volatile("s_waitcnt lgkmcnt(0)" ::: "memory");
            __builtin_amdgcn_sched_barrier(0);
            mfmaq<2>(acc, af, bfr);
            __builtin_amdgcn_s_barrier();
        }
        // ---- phase 3: A q3, counted vmcnt for next tile ----
        {
            bf16x8 af[2][2];
            ldA(af, AsB, 3);
            if (t < NT - 2)       asm volatile("s_waitcnt vmcnt(4)" ::: "memory");
            else if (t == NT - 2) asm volatile("s_waitcnt vmcnt(0)" ::: "memory");
            __builtin_amdgcn_s_barrier();
            asm volatile("s_waitcnt lgkmcnt(0)" ::: "memory");
            __builtin_amdgcn_sched_barrier(0);
            mfmaq<3>(acc, af, bfr);
            __builtin_amdgcn_s_barrier();
        }
    }

    // ---- epilogue: C bf16 ----
#pragma unroll
    for (int mf = 0; mf < 8; mf++) {
        const int row = bm * 256 + wm + mf * 16 + quad * 4;
#pragma unroll
        for (int nt = 0; nt < 4; nt++) {
            const int col = bn * 256 + wn + nt * 16 + l16;
#pragma unroll
            for (int r = 0; r < 4; r++)
                C[(size_t)(row + r) * N + col] = f2bf(acc[mf][nt][r]);
        }
    }
}

// ---------------------------------------------------------------------------
// gemm_proj: C[M,N](f32) = A[M,K] @ B[N,K]^T + bias, 64x128 tile.
// Grid 8x64 = 512 blocks = 2/CU.  R2 measured ~13 us gain.  KEEP.
// ---------------------------------------------------------------------------
__global__ __launch_bounds__(256) void gemm_proj(
    const unsigned short* __restrict__ A, const unsigned short* __restrict__ B,
    const float* __restrict__ bias, float* __restrict__ C, int M, int N, int K)
{
    __shared__ __align__(16) unsigned short As[64 * 32];
    __shared__ __align__(16) unsigned short Bs[128 * 32];

    const int tid = threadIdx.x;
    const int bn = blockIdx.x, bm = blockIdx.y;   // bn 0..7, bm 0..63
    const int w = tid >> 6, lane = tid & 63;
    const int quad = lane >> 4, l16 = lane & 15;
    const int wm = (w >> 1) * 32, wn = (w & 1) * 64;   // wave tile 32x64

    f32x4 acc[2][4] = {};

    const int srow = w * 16 + (lane >> 2);
    const int scol = (lane & 3) * 8;
    const unsigned short* Ag = &A[(size_t)(bm * 64 + srow) * K + scol];
    const unsigned short* Bg = &B[(size_t)(bn * 128 + srow) * K + scol];
    unsigned short* AsW = &As[(w * 16) * 32];
    unsigned short* BsW = &Bs[(w * 16) * 32];

    for (int k0 = 0; k0 < K; k0 += 32) {
        gl2lds16(Ag + k0, AsW);
        gl2lds16(Bg + k0, BsW);
        gl2lds16(Bg + (size_t)64 * K + k0, BsW + 64 * 32);
        __syncthreads();

        bf16x8 af[2], bfr[4];
#pragma unroll
        for (int t = 0; t < 2; t++)
            af[t]  = *(const bf16x8*)&As[(wm + t * 16 + l16) * 32 + quad * 8];
#pragma unroll
        for (int t = 0; t < 4; t++)
            bfr[t] = *(const bf16x8*)&Bs[(wn + t * 16 + l16) * 32 + quad * 8];
#pragma unroll
        for (int mt = 0; mt < 2; mt++)
#pragma unroll
            for (int nt = 0; nt < 4; nt++)
                acc[mt][nt] = __builtin_amdgcn_mfma_f32_16x16x32_bf16(
                    af[mt], bfr[nt], acc[mt][nt], 0, 0, 0);
        __syncthreads();
    }

#pragma unroll
    for (int mt = 0; mt < 2; mt++) {
        const int row = bm * 64 + wm + mt * 16 + quad * 4;
#pragma unroll
        for (int nt = 0; nt < 4; nt++) {
            const int col = bn * 128 + wn + nt * 16 + l16;
            const float bv = bias[col];
#pragma unroll
            for (int r = 0; r < 4; r++)
                C[(size_t)(row + r) * N + col] = acc[mt][nt][r] + bv;
        }
    }
}

// ---------------------------------------------------------------------------
// Fused causal flash attention — R4-exact (best measured: 51.5 us, occ 26.5%,
// 0 bank conflicts).  R6 lesson: removing the B2 barrier HURT (54.2; barrier
// keeps waves phase-interleaved + overlaps Ps-store drain across waves).
// ---------------------------------------------------------------------------
__global__ __launch_bounds__(256) void attn_fused(
    const unsigned short* __restrict__ kqv,
    unsigned short* __restrict__ out)
{
    __shared__ __align__(16) unsigned short Qs[64 * 64];
    __shared__ __align__(16) unsigned short Ks[2][64 * 64];
    __shared__ __align__(16) unsigned short Vts[2][64 * 64];
    __shared__ __align__(16) unsigned short Ps[64 * 64];

    const int bh = blockIdx.x;                 // 0..31  (bh%8 = XCD)
    const int qt = 31 - (int)blockIdx.y;       // heavy tiles first
    const int b = bh >> 4, h = bh & 15;
    const int tid = threadIdx.x;
    const int w = tid >> 6;                    // wave 0..3
    const int lane = tid & 63;
    const int quad = lane >> 4, l16 = lane & 15;
    const int rowBase = b * 2048;
    const int kOff = h * 64, qOff = 1024 + h * 64, vOff = 2048 + h * 64;
    const float SEXP = 0.125f * 1.4426950408889634f;   // D^-0.5 folded into exp2
    const float MASKV = -1.0e30f;

    // ---- stage Q (swizzled) ----
#pragma unroll
    for (int i = 0; i < 2; i++) {
        const int v = tid + i * 256;
        const int row = v >> 3, c8 = (v & 7) * 8;
        *(u16x8*)swz(Qs, row, c8) =
            *(const u16x8*)&kqv[(size_t)(rowBase + qt * 64 + row) * 3072 + qOff + c8];
    }

    f32x4 o[4] = {};
    float l_i[4] = {0.f, 0.f, 0.f, 0.f};

    // ---- register prefetch of tile j=0 ----
    u16x8 kr[2], vr[2];
#pragma unroll
    for (int i = 0; i < 2; i++) {
        const int v = tid + i * 256;
        kr[i] = *(const u16x8*)&kqv[(size_t)(rowBase + (v >> 3)) * 3072 + kOff + (v & 7) * 8];
        vr[i] = *(const u16x8*)&kqv[(size_t)(rowBase + lane) * 3072 + vOff + (i * 4 + w) * 8];
    }

    for (int j = 0; j <= qt; j++) {
        const int cur = j & 1;
        // ---- regs -> LDS[cur] (K row-major; V transposed, kv=lane) ----
#pragma unroll
        for (int i = 0; i < 2; i++) {
            const int v = tid + i * 256;
            *(u16x8*)swz(Ks[cur], v >> 3, (v & 7) * 8) = kr[i];
            const int d8 = i * 4 + w;
#pragma unroll
            for (int u = 0; u < 8; u++)        // row&7 == u -> XOR is unroll-const
                *swz(Vts[cur], d8 * 8 + u, lane) = vr[i][u];
        }
        __syncthreads();   // Btop: tile j (and Qs at j=0) visible; prior-buffer
                           // reads AND prior-iter Ps reads drained

        // ---- prefetch tile j+1 into registers ----
        if (j < qt) {
#pragma unroll
            for (int i = 0; i < 2; i++) {
                const int v = tid + i * 256;
                kr[i] = *(const u16x8*)&kqv[(size_t)(rowBase + (j + 1) * 64 + (v >> 3)) * 3072 + kOff + (v & 7) * 8];
                vr[i] = *(const u16x8*)&kqv[(size_t)(rowBase + (j + 1) * 64 + lane) * 3072 + vOff + (i * 4 + w) * 8];
            }
        }

        // ---- S = Q K^T ----
        f32x4 s[4] = {};
#pragma unroll
        for (int ks = 0; ks < 2; ks++) {
            const bf16x8 aq = *(const bf16x8*)swz(Qs, w * 16 + l16, ks * 32 + quad * 8);
#pragma unroll
            for (int nt = 0; nt < 4; nt++) {
                const bf16x8 bk = *(const bf16x8*)swz(Ks[cur], nt * 16 + l16, ks * 32 + quad * 8);
                s[nt] = __builtin_amdgcn_mfma_f32_16x16x32_bf16(aq, bk, s[nt], 0, 0, 0);
            }
        }

        if (j == qt) {                 // diagonal tile: mask col > row
            const int rowl = w * 16 + quad * 4;
#pragma unroll
            for (int nt = 0; nt < 4; nt++) {
                const int coll = nt * 16 + l16;
#pragma unroll
                for (int r = 0; r < 4; r++)
                    if (coll > rowl + r) s[nt][r] = MASKV;
            }
        }

        // ---- P = exp2(S*c); l += P; store P (single buffer) ----
#pragma unroll
        for (int nt = 0; nt < 4; nt++) {
#pragma unroll
            for (int r = 0; r < 4; r++) {
                const float p = exp2f(s[nt][r] * SEXP);
                l_i[r] += p;
                *swz(Ps, w * 16 + quad * 4 + r, nt * 16 + l16) = f2bf(p);
            }
        }
        __syncthreads();   // B2: P visible (R6: removing this costs ~3 us)

        // ---- O += P @ V ----
#pragma unroll
        for (int ks = 0; ks < 2; ks++) {
            const bf16x8 ap = *(const bf16x8*)swz(Ps, w * 16 + l16, ks * 32 + quad * 8);
#pragma unroll
            for (int nt = 0; nt < 4; nt++) {
                const bf16x8 bv = *(const bf16x8*)swz(Vts[cur], nt * 16 + l16, ks * 32 + quad * 8);
                o[nt] = __builtin_amdgcn_mfma_f32_16x16x32_bf16(ap, bv, o[nt], 0, 0, 0);
            }
        }
        // no trailing barrier: next iter stages the OTHER K/V buffer; its Btop
        // orders those writes (and the next Ps write) after this iter's reads.
    }

    // ---- one cross-lane l reduction per q-tile ----
    float linv[4];
#pragma unroll
    for (int r = 0; r < 4; r++) {
        float t = l_i[r];
        t += __shfl_xor(t, 1);
        t += __shfl_xor(t, 2);
        t += __shfl_xor(t, 4);
        t += __shfl_xor(t, 8);
        linv[r] = 1.0f / t;
    }

    // ---- epilogue: O * (1/l) -> bf16 attn [B,T,H*D] ----
#pragma unroll
    for (int nt = 0; nt < 4; nt++) {
        const int col = h * 64 + nt * 16 + l16;
#pragma unroll
        for (int r = 0; r < 4; r++)
            out[(size_t)(rowBase + qt * 64 + w * 16 + quad * 4 + r) * 1024 + col] =
                f2bf(o[nt][r] * linv[r]);
    }
}

// ---------------------------------------------------------------------------
extern "C" void kernel_launch(void* const* d_in, const int* in_sizes, int n_in,
                              void* d_out, int out_size, void* d_ws, size_t ws_size,
                              hipStream_t stream) {
    const float* x     = (const float*)d_in[0];   // [4096][1024]
    const float* Wkqv  = (const float*)d_in[1];   // [3072][1024]
    const float* Wproj = (const float*)d_in[2];   // [1024][1024]
    const float* bproj = (const float*)d_in[3];   // [1024]
    float* out = (float*)d_out;                   // FP32

    unsigned short* kqv    = (unsigned short*)d_ws;
    unsigned short* attn   = kqv    + (size_t)4096 * 3072;
    unsigned short* xb     = attn   + (size_t)4096 * 1024;
    unsigned short* wkqvb  = xb     + (size_t)4096 * 1024;
    unsigned short* wprojb = wkqvb  + (size_t)3072 * 1024;

    cvt_bf16_3<<<dim3(512), dim3(256), 0, stream>>>(
        x, xb, 4096 * 1024, Wkqv, wkqvb, 3072 * 1024, Wproj, wprojb, 1024 * 1024);

    gemm_qkv<<<dim3(12, 16), dim3(512), 0, stream>>>(
        xb, wkqvb, kqv, 4096, 3072, 1024);

    attn_fused<<<dim3(32, 32), dim3(256), 0, stream>>>(kqv, attn);

    gemm_proj<<<dim3(8, 64), dim3(256), 0, stream>>>(
        attn, wprojb, bproj, out, 4096, 1024, 1024);
}

// Round 8
// 180.249 us; speedup vs baseline: 1.0145x; 1.0145x over previous
//
#include <hip/hip_runtime.h>
#include <cstdint>

// B=2, T=2048, C=1024, H=16, D=64 -> M = 4096.
// Inputs fp32 (dict order), OUTPUT FP32 (proven R7/R8). ws >= 64 MiB.
// Split order: k=[0,1024) q=[1024,2048) v=[2048,3072).
// ws layout (bf16): kqv 25.2MB | attn 8.4MB | xb 8.4MB | wkqvb 6.3MB | wprojb 2.1MB

typedef __bf16 bf16x8 __attribute__((ext_vector_type(8)));
typedef unsigned short u16x8 __attribute__((ext_vector_type(8)));
typedef float f32x4 __attribute__((ext_vector_type(4)));

__device__ __forceinline__ float bf2f(unsigned short u) {
    return __uint_as_float(((unsigned int)u) << 16);
}
__device__ __forceinline__ unsigned short f2bf(float f) {
    unsigned int u = __float_as_uint(f);
    u += 0x7fffu + ((u >> 16) & 1u);   // RNE
    return (unsigned short)(u >> 16);
}
__device__ __forceinline__ void stC(float* p, float v) { *p = v; }
__device__ __forceinline__ void stC(unsigned short* p, float v) { *p = f2bf(v); }

// async 16B global->LDS (DMA; LDS dest = wave-uniform base + lane*16)
__device__ __forceinline__ void gl2lds16(const unsigned short* g, unsigned short* l) {
    __builtin_amdgcn_global_load_lds(
        (__attribute__((address_space(1))) void*)g,
        (__attribute__((address_space(3))) void*)l, 16, 0, 0);
}

// XOR-swizzled LDS addressing for stride-64-short (128 B) rows:
// byte_off = row*128 + col*2, XOR'd with ((row&7)<<4).  Measured 0 conflicts
// for the 16-consecutive-rows fragment-read pattern (R1).
__device__ __forceinline__ unsigned short* swz(unsigned short* base, int row, int col) {
    const int off = ((row << 7) + (col << 1)) ^ ((row & 7) << 4);
    return (unsigned short*)((char*)base + off);
}
__device__ __forceinline__ const unsigned short* swz(const unsigned short* base, int row, int col) {
    const int off = ((row << 7) + (col << 1)) ^ ((row & 7) << 4);
    return (const unsigned short*)((const char*)base + off);
}

// ---------------------------------------------------------------------------
// fp32 -> bf16 bulk convert, three tensors in one launch
// ---------------------------------------------------------------------------
__device__ __forceinline__ void cvt8(const float* __restrict__ s, unsigned short* __restrict__ d) {
    const f32x4 a = *(const f32x4*)s;
    const f32x4 b = *(const f32x4*)(s + 4);
    u16x8 o;
    o[0] = f2bf(a[0]); o[1] = f2bf(a[1]); o[2] = f2bf(a[2]); o[3] = f2bf(a[3]);
    o[4] = f2bf(b[0]); o[5] = f2bf(b[1]); o[6] = f2bf(b[2]); o[7] = f2bf(b[3]);
    *(u16x8*)d = o;
}
__global__ __launch_bounds__(256) void cvt_bf16_3(
    const float* __restrict__ s0, unsigned short* __restrict__ d0, int n0,
    const float* __restrict__ s1, unsigned short* __restrict__ d1, int n1,
    const float* __restrict__ s2, unsigned short* __restrict__ d2, int n2)
{
    const int t = blockIdx.x * 256 + threadIdx.x;
    const int S = gridDim.x * 256;
    for (int i = t; i < n0 / 8; i += S) cvt8(s0 + (size_t)i * 8, d0 + (size_t)i * 8);
    for (int i = t; i < n1 / 8; i += S) cvt8(s1 + (size_t)i * 8, d1 + (size_t)i * 8);
    for (int i = t; i < n2 / 8; i += S) cvt8(s2 + (size_t)i * 8, d2 + (size_t)i * 8);
}

// ---------------------------------------------------------------------------
// gemm_qkv v2: 8-phase 256x256 schedule (R7: passed, ties 2-phase BK64 at
// this shape; kept — higher ceiling, correctness-proven).
// ---------------------------------------------------------------------------
template <int P>
__device__ __forceinline__ void mfmaq(f32x4 (&acc)[8][4],
                                      const bf16x8 (&af)[2][2],
                                      const bf16x8 (&bfr)[4][2]) {
#pragma unroll
    for (int m2 = 0; m2 < 2; m2++)
#pragma unroll
        for (int nt = 0; nt < 4; nt++)
#pragma unroll
            for (int ks = 0; ks < 2; ks++)
                acc[2 * P + m2][nt] = __builtin_amdgcn_mfma_f32_16x16x32_bf16(
                    af[m2][ks], bfr[nt][ks], acc[2 * P + m2][nt], 0, 0, 0);
}

__global__ __launch_bounds__(512) void gemm_qkv(
    const unsigned short* __restrict__ A, const unsigned short* __restrict__ B,
    unsigned short* __restrict__ C, int M, int N, int K)
{
    __shared__ __align__(16) unsigned short As[2][256 * 64];
    __shared__ __align__(16) unsigned short Bs[2][256 * 64];

    const int tid = threadIdx.x;
    const int bn = blockIdx.x, bm = blockIdx.y;
    const int w = tid >> 6, lane = tid & 63;
    const int quad = lane >> 4, l16 = lane & 15;
    const int wm = (w >> 2) * 128, wn = (w & 3) * 64;
    const int NT = K >> 6;                      // 16 K-tiles

    f32x4 acc[8][4] = {};

    const int srow8 = lane >> 3;                // 0..7 within 8-row group
    const int scol = ((lane & 7) ^ srow8) * 8;  // inverse-swizzled source col
    const unsigned short* Ab = A + (size_t)bm * 256 * K;
    const unsigned short* Bb = B + (size_t)bn * 256 * K;

    auto stage = [&](const unsigned short* __restrict__ G, unsigned short* lds,
                     int tT, int hh) {
#pragma unroll
        for (int i = 0; i < 2; i++) {
            const int r = hh * 128 + w * 16 + i * 8;      // wave-uniform
            gl2lds16(G + (size_t)(r + srow8) * K + tT * 64 + scol, lds + r * 64);
        }
    };
    auto ldA = [&](bf16x8 (&af)[2][2], const unsigned short* AsB, int p) {
#pragma unroll
        for (int m2 = 0; m2 < 2; m2++)
#pragma unroll
            for (int ks = 0; ks < 2; ks++)
                af[m2][ks] = *(const bf16x8*)swz(AsB, wm + p * 32 + m2 * 16 + l16,
                                                 ks * 32 + quad * 8);
    };
    auto ldB = [&](bf16x8 (&bf_)[4][2], const unsigned short* BsB) {
#pragma unroll
        for (int nt = 0; nt < 4; nt++)
#pragma unroll
            for (int ks = 0; ks < 2; ks++)
                bf_[nt][ks] = *(const bf16x8*)swz(BsB, wn + nt * 16 + l16,
                                                  ks * 32 + quad * 8);
    };

    // ---- prologue: B(0), A(0), B(1); wait tile-0 resident (B(1) in flight) ----
    stage(Bb, Bs[0], 0, 0); stage(Bb, Bs[0], 0, 1);
    stage(Ab, As[0], 0, 0); stage(Ab, As[0], 0, 1);
    stage(Bb, Bs[1], 1, 0); stage(Bb, Bs[1], 1, 1);
    asm volatile("s_waitcnt vmcnt(4)" ::: "memory");
    __builtin_amdgcn_s_barrier();

    for (int t = 0; t < NT; t++) {
        const unsigned short* AsB = As[t & 1];
        const unsigned short* BsB = Bs[t & 1];
        unsigned short* AsN = As[(t + 1) & 1];
        unsigned short* BsN = Bs[t & 1];        // (t+2)&1 == t&1
        bf16x8 bfr[4][2];
        // ---- phase 0: 12 ds_reads (A q0 + all B), stage A0(t+1) ----
        {
            bf16x8 af[2][2];
            ldA(af, AsB, 0);
            ldB(bfr, BsB);
            if (t + 1 < NT) stage(Ab, AsN, t + 1, 0);
            __builtin_amdgcn_s_barrier();
            asm volatile("s_waitcnt lgkmcnt(0)" ::: "memory");
            __builtin_amdgcn_sched_barrier(0);
            mfmaq<0>(acc, af, bfr);
            __builtin_amdgcn_s_barrier();
        }
        // ---- phase 1: A q1, stage A1(t+1) + B0(t+2) ----
        {
            bf16x8 af[2][2];
            ldA(af, AsB, 1);
            if (t + 1 < NT) stage(Ab, AsN, t + 1, 1);
            if (t + 2 < NT) stage(Bb, BsN, t + 2, 0);
            __builtin_amdgcn_s_barrier();
            asm volatile("s_waitcnt lgkmcnt(0)" ::: "memory");
            __builtin_amdgcn_sched_barrier(0);
            mfmaq<1>(acc, af, bfr);
            __builtin_amdgcn_s_barrier();
        }
        // ---- phase 2: A q2, stage B1(t+2) ----
        {
            bf16x8 af[2][2];
            ldA(af, AsB, 2);
            if (t + 2 < NT) stage(Bb, BsN, t + 2, 1);
            __builtin_amdgcn_s_barrier();
            asm volatile("s_waitcnt lgkmcnt(0)" ::: "memory");
            __builtin_amdgcn_sched_barrier(0);
            mfmaq<2>(acc, af, bfr);
            __builtin_amdgcn_s_barrier();
        }
        // ---- phase 3: A q3, counted vmcnt for next tile ----
        {
            bf16x8 af[2][2];
            ldA(af, AsB, 3);
            if (t < NT - 2)       asm volatile("s_waitcnt vmcnt(4)" ::: "memory");
            else if (t == NT - 2) asm volatile("s_waitcnt vmcnt(0)" ::: "memory");
            __builtin_amdgcn_s_barrier();
            asm volatile("s_waitcnt lgkmcnt(0)" ::: "memory");
            __builtin_amdgcn_sched_barrier(0);
            mfmaq<3>(acc, af, bfr);
            __builtin_amdgcn_s_barrier();
        }
    }

    // ---- epilogue: C bf16 ----
#pragma unroll
    for (int mf = 0; mf < 8; mf++) {
        const int row = bm * 256 + wm + mf * 16 + quad * 4;
#pragma unroll
        for (int nt = 0; nt < 4; nt++) {
            const int col = bn * 256 + wn + nt * 16 + l16;
#pragma unroll
            for (int r = 0; r < 4; r++)
                C[(size_t)(row + r) * N + col] = f2bf(acc[mf][nt][r]);
        }
    }
}

// ---------------------------------------------------------------------------
// gemm_proj v2: 64x128 tile (R2-proven 2/CU), BK 32->64 with the proven
// swizzle involution (R4 qkv pattern): half the barrier drains, LDS 24 KiB.
// ---------------------------------------------------------------------------
__global__ __launch_bounds__(256) void gemm_proj(
    const unsigned short* __restrict__ A, const unsigned short* __restrict__ B,
    const float* __restrict__ bias, float* __restrict__ C, int M, int N, int K)
{
    __shared__ __align__(16) unsigned short As[64 * 64];
    __shared__ __align__(16) unsigned short Bs[128 * 64];

    const int tid = threadIdx.x;
    const int bn = blockIdx.x, bm = blockIdx.y;   // bn 0..7, bm 0..63
    const int w = tid >> 6, lane = tid & 63;
    const int quad = lane >> 4, l16 = lane & 15;
    const int wm = (w >> 1) * 32, wn = (w & 1) * 64;   // wave tile 32x64

    f32x4 acc[2][4] = {};

    const int srow8 = lane >> 3;                // 0..7 within 8-row group
    const int scol = ((lane & 7) ^ srow8) * 8;  // inverse-swizzled source col
    const unsigned short* Ag = &A[(size_t)(bm * 64 + w * 16 + srow8) * K + scol];
    const unsigned short* Bg = &B[(size_t)(bn * 128 + w * 32 + srow8) * K + scol];
    unsigned short* AsW = &As[(w * 16) * 64];
    unsigned short* BsW = &Bs[(w * 32) * 64];

    for (int k0 = 0; k0 < K; k0 += 64) {
#pragma unroll
        for (int i = 0; i < 2; i++)
            gl2lds16(Ag + (size_t)(i * 8) * K + k0, AsW + i * 8 * 64);
#pragma unroll
        for (int i = 0; i < 4; i++)
            gl2lds16(Bg + (size_t)(i * 8) * K + k0, BsW + i * 8 * 64);
        __syncthreads();

#pragma unroll
        for (int ks = 0; ks < 2; ks++) {
            bf16x8 af[2], bfr[4];
#pragma unroll
            for (int t = 0; t < 2; t++)
                af[t]  = *(const bf16x8*)swz(As, wm + t * 16 + l16, ks * 32 + quad * 8);
#pragma unroll
            for (int t = 0; t < 4; t++)
                bfr[t] = *(const bf16x8*)swz(Bs, wn + t * 16 + l16, ks * 32 + quad * 8);
#pragma unroll
            for (int mt = 0; mt < 2; mt++)
#pragma unroll
                for (int nt = 0; nt < 4; nt++)
                    acc[mt][nt] = __builtin_amdgcn_mfma_f32_16x16x32_bf16(
                        af[mt], bfr[nt], acc[mt][nt], 0, 0, 0);
        }
        __syncthreads();
    }

#pragma unroll
    for (int mt = 0; mt < 2; mt++) {
        const int row = bm * 64 + wm + mt * 16 + quad * 4;
#pragma unroll
        for (int nt = 0; nt < 4; nt++) {
            const int col = bn * 128 + wn + nt * 16 + l16;
            const float bv = bias[col];
#pragma unroll
            for (int r = 0; r < 4; r++)
                C[(size_t)(row + r) * N + col] = acc[mt][nt][r] + bv;
        }
    }
}

// ---------------------------------------------------------------------------
// Fused causal flash attention v10 = R4 structure (proven 50.2-51.5 us) with
// two VALU reductions (VALUBusy 57.8% is the measured busiest pipe):
//  1. Q pre-scaled at staging by 0.125*log2e -> removes 16 v_mul/iter/wave;
//     exp2f applied directly to S (masked -1e30 -> exp2 = 0 unchanged).
//  2. K/V prefetch pointers strength-reduced: 4 persistent pointers advanced
//     by the constant 64*3072 stride instead of rebuilt 64-bit addr chains.
// Everything else byte-identical to the R4/R7 attn (B2 kept per R6 lesson).
// ---------------------------------------------------------------------------
__global__ __launch_bounds__(256) void attn_fused(
    const unsigned short* __restrict__ kqv,
    unsigned short* __restrict__ out)
{
    __shared__ __align__(16) unsigned short Qs[64 * 64];
    __shared__ __align__(16) unsigned short Ks[2][64 * 64];
    __shared__ __align__(16) unsigned short Vts[2][64 * 64];
    __shared__ __align__(16) unsigned short Ps[64 * 64];

    const int bh = blockIdx.x;                 // 0..31  (bh%8 = XCD)
    const int qt = 31 - (int)blockIdx.y;       // heavy tiles first
    const int b = bh >> 4, h = bh & 15;
    const int tid = threadIdx.x;
    const int w = tid >> 6;                    // wave 0..3
    const int lane = tid & 63;
    const int quad = lane >> 4, l16 = lane & 15;
    const int rowBase = b * 2048;
    const int kOff = h * 64, qOff = 1024 + h * 64, vOff = 2048 + h * 64;
    const float SEXP = 0.125f * 1.4426950408889634f;   // D^-0.5 folded into exp2
    const float MASKV = -1.0e30f;

    // ---- stage Q (swizzled), PRE-SCALED by SEXP in f32 ----
#pragma unroll
    for (int i = 0; i < 2; i++) {
        const int v = tid + i * 256;
        const int row = v >> 3, c8 = (v & 7) * 8;
        const u16x8 raw =
            *(const u16x8*)&kqv[(size_t)(rowBase + qt * 64 + row) * 3072 + qOff + c8];
        u16x8 sc;
#pragma unroll
        for (int e = 0; e < 8; e++) sc[e] = f2bf(bf2f(raw[e]) * SEXP);
        *(u16x8*)swz(Qs, row, c8) = sc;
    }

    f32x4 o[4] = {};
    float l_i[4] = {0.f, 0.f, 0.f, 0.f};

    // ---- prefetch pointers (advance by 64 rows per j-iter) ----
    const ptrdiff_t KV = (ptrdiff_t)64 * 3072;
    const unsigned short* kp0 = &kqv[(size_t)(rowBase + (tid >> 3)) * 3072 + kOff + (tid & 7) * 8];
    const unsigned short* kp1 = kp0 + (ptrdiff_t)32 * 3072;
    const unsigned short* vp0 = &kqv[(size_t)(rowBase + lane) * 3072 + vOff + w * 8];
    const unsigned short* vp1 = vp0 + 32;

    // ---- register prefetch of tile j=0 ----
    u16x8 kr[2], vr[2];
    kr[0] = *(const u16x8*)kp0;  kr[1] = *(const u16x8*)kp1;
    vr[0] = *(const u16x8*)vp0;  vr[1] = *(const u16x8*)vp1;

    for (int j = 0; j <= qt; j++) {
        const int cur = j & 1;
        // ---- regs -> LDS[cur] (K row-major; V transposed, kv=lane) ----
#pragma unroll
        for (int i = 0; i < 2; i++) {
            const int v = tid + i * 256;
            *(u16x8*)swz(Ks[cur], v >> 3, (v & 7) * 8) = kr[i];
            const int d8 = i * 4 + w;
#pragma unroll
            for (int u = 0; u < 8; u++)        // row&7 == u -> XOR is unroll-const
                *swz(Vts[cur], d8 * 8 + u, lane) = vr[i][u];
        }
        __syncthreads();   // Btop: tile j (and Qs at j=0) visible; prior-buffer
                           // reads AND prior-iter Ps reads drained

        // ---- prefetch tile j+1 into registers ----
        if (j < qt) {
            kp0 += KV; kp1 += KV; vp0 += KV; vp1 += KV;
            kr[0] = *(const u16x8*)kp0;  kr[1] = *(const u16x8*)kp1;
            vr[0] = *(const u16x8*)vp0;  vr[1] = *(const u16x8*)vp1;
        }

        // ---- S = Q K^T (Q pre-scaled) ----
        f32x4 s[4] = {};
#pragma unroll
        for (int ks = 0; ks < 2; ks++) {
            const bf16x8 aq = *(const bf16x8*)swz(Qs, w * 16 + l16, ks * 32 + quad * 8);
#pragma unroll
            for (int nt = 0; nt < 4; nt++) {
                const bf16x8 bk = *(const bf16x8*)swz(Ks[cur], nt * 16 + l16, ks * 32 + quad * 8);
                s[nt] = __builtin_amdgcn_mfma_f32_16x16x32_bf16(aq, bk, s[nt], 0, 0, 0);
            }
        }

        if (j == qt) {                 // diagonal tile: mask col > row
            const int rowl = w * 16 + quad * 4;
#pragma unroll
            for (int nt = 0; nt < 4; nt++) {
                const int coll = nt * 16 + l16;
#pragma unroll
                for (int r = 0; r < 4; r++)
                    if (coll > rowl + r) s[nt][r] = MASKV;
            }
        }

        // ---- P = exp2(S); l += P; store P (single buffer) ----
#pragma unroll
        for (int nt = 0; nt < 4; nt++) {
#pragma unroll
            for (int r = 0; r < 4; r++) {
                const float p = exp2f(s[nt][r]);
                l_i[r] += p;
                *swz(Ps, w * 16 + quad * 4 + r, nt * 16 + l16) = f2bf(p);
            }
        }
        __syncthreads();   // B2: P visible (R6: removing this costs ~3 us)

        // ---- O += P @ V ----
#pragma unroll
        for (int ks = 0; ks < 2; ks++) {
            const bf16x8 ap = *(const bf16x8*)swz(Ps, w * 16 + l16, ks * 32 + quad * 8);
#pragma unroll
            for (int nt = 0; nt < 4; nt++) {
                const bf16x8 bv = *(const bf16x8*)swz(Vts[cur], nt * 16 + l16, ks * 32 + quad * 8);
                o[nt] = __builtin_amdgcn_mfma_f32_16x16x32_bf16(ap, bv, o[nt], 0, 0, 0);
            }
        }
        // no trailing barrier: next iter stages the OTHER K/V buffer; its Btop
        // orders those writes (and the next Ps write) after this iter's reads.
    }

    // ---- one cross-lane l reduction per q-tile ----
    float linv[4];
#pragma unroll
    for (int r = 0; r < 4; r++) {
        float t = l_i[r];
        t += __shfl_xor(t, 1);
        t += __shfl_xor(t, 2);
        t += __shfl_xor(t, 4);
        t += __shfl_xor(t, 8);
        linv[r] = 1.0f / t;
    }

    // ---- epilogue: O * (1/l) -> bf16 attn [B,T,H*D] ----
#pragma unroll
    for (int nt = 0; nt < 4; nt++) {
        const int col = h * 64 + nt * 16 + l16;
#pragma unroll
        for (int r = 0; r < 4; r++)
            out[(size_t)(rowBase + qt * 64 + w * 16 + quad * 4 + r) * 1024 + col] =
                f2bf(o[nt][r] * linv[r]);
    }
}

// ---------------------------------------------------------------------------
extern "C" void kernel_launch(void* const* d_in, const int* in_sizes, int n_in,
                              void* d_out, int out_size, void* d_ws, size_t ws_size,
                              hipStream_t stream) {
    const float* x     = (const float*)d_in[0];   // [4096][1024]
    const float* Wkqv  = (const float*)d_in[1];   // [3072][1024]
    const float* Wproj = (const float*)d_in[2];   // [1024][1024]
    const float* bproj = (const float*)d_in[3];   // [1024]
    float* out = (float*)d_out;                   // FP32

    unsigned short* kqv    = (unsigned short*)d_ws;
    unsigned short* attn   = kqv    + (size_t)4096 * 3072;
    unsigned short* xb     = attn   + (size_t)4096 * 1024;
    unsigned short* wkqvb  = xb     + (size_t)4096 * 1024;
    unsigned short* wprojb = wkqvb  + (size_t)3072 * 1024;

    cvt_bf16_3<<<dim3(512), dim3(256), 0, stream>>>(
        x, xb, 4096 * 1024, Wkqv, wkqvb, 3072 * 1024, Wproj, wprojb, 1024 * 1024);

    gemm_qkv<<<dim3(12, 16), dim3(512), 0, stream>>>(
        xb, wkqvb, kqv, 4096, 3072, 1024);

    attn_fused<<<dim3(32, 32), dim3(256), 0, stream>>>(kqv, attn);

    gemm_proj<<<dim3(8, 64), dim3(256), 0, stream>>>(
        attn, wprojb, bproj, out, 4096, 1024, 1024);
}

// Round 9
// 178.107 us; speedup vs baseline: 1.0267x; 1.0120x over previous
//
#include <hip/hip_runtime.h>
#include <cstdint>

// B=2, T=2048, C=1024, H=16, D=64 -> M = 4096.
// Inputs fp32 (dict order), OUTPUT FP32 (proven R7/R8). ws >= 64 MiB.
// Split order: k=[0,1024) q=[1024,2048) v=[2048,3072).
// ws layout (bf16): kqv 25.2MB | attn 8.4MB | xb 8.4MB | wkqvb 6.3MB | wprojb 2.1MB

typedef __bf16 bf16x8 __attribute__((ext_vector_type(8)));
typedef unsigned short u16x8 __attribute__((ext_vector_type(8)));
typedef float f32x4 __attribute__((ext_vector_type(4)));

__device__ __forceinline__ float bf2f(unsigned short u) {
    return __uint_as_float(((unsigned int)u) << 16);
}
__device__ __forceinline__ unsigned short f2bf(float f) {
    unsigned int u = __float_as_uint(f);
    u += 0x7fffu + ((u >> 16) & 1u);   // RNE
    return (unsigned short)(u >> 16);
}
__device__ __forceinline__ void stC(float* p, float v) { *p = v; }
__device__ __forceinline__ void stC(unsigned short* p, float v) { *p = f2bf(v); }

// async 16B global->LDS (DMA; LDS dest = wave-uniform base + lane*16)
__device__ __forceinline__ void gl2lds16(const unsigned short* g, unsigned short* l) {
    __builtin_amdgcn_global_load_lds(
        (__attribute__((address_space(1))) void*)g,
        (__attribute__((address_space(3))) void*)l, 16, 0, 0);
}

// XOR-swizzled LDS addressing for stride-64-short (128 B) rows:
// byte_off = row*128 + col*2, XOR'd with ((row&7)<<4).  Measured 0 conflicts
// for the 16-consecutive-rows fragment-read pattern (R1).
__device__ __forceinline__ unsigned short* swz(unsigned short* base, int row, int col) {
    const int off = ((row << 7) + (col << 1)) ^ ((row & 7) << 4);
    return (unsigned short*)((char*)base + off);
}
__device__ __forceinline__ const unsigned short* swz(const unsigned short* base, int row, int col) {
    const int off = ((row << 7) + (col << 1)) ^ ((row & 7) << 4);
    return (const unsigned short*)((const char*)base + off);
}

// ---------------------------------------------------------------------------
// fp32 -> bf16 bulk convert, three tensors in one launch
// ---------------------------------------------------------------------------
__device__ __forceinline__ void cvt8(const float* __restrict__ s, unsigned short* __restrict__ d) {
    const f32x4 a = *(const f32x4*)s;
    const f32x4 b = *(const f32x4*)(s + 4);
    u16x8 o;
    o[0] = f2bf(a[0]); o[1] = f2bf(a[1]); o[2] = f2bf(a[2]); o[3] = f2bf(a[3]);
    o[4] = f2bf(b[0]); o[5] = f2bf(b[1]); o[6] = f2bf(b[2]); o[7] = f2bf(b[3]);
    *(u16x8*)d = o;
}
__global__ __launch_bounds__(256) void cvt_bf16_3(
    const float* __restrict__ s0, unsigned short* __restrict__ d0, int n0,
    const float* __restrict__ s1, unsigned short* __restrict__ d1, int n1,
    const float* __restrict__ s2, unsigned short* __restrict__ d2, int n2)
{
    const int t = blockIdx.x * 256 + threadIdx.x;
    const int S = gridDim.x * 256;
    for (int i = t; i < n0 / 8; i += S) cvt8(s0 + (size_t)i * 8, d0 + (size_t)i * 8);
    for (int i = t; i < n1 / 8; i += S) cvt8(s1 + (size_t)i * 8, d1 + (size_t)i * 8);
    for (int i = t; i < n2 / 8; i += S) cvt8(s2 + (size_t)i * 8, d2 + (size_t)i * 8);
}

// ---------------------------------------------------------------------------
// gemm_qkv v3: 8-phase 256x256 schedule (R7, correctness-proven) + T1
// XCD-aware bijective block swizzle.  Grid = 192 blocks = 1 block/CU ->
// no inter-block overlap per CU; default round-robin scatters same-A-panel
// tiles across XCDs.  Remap (192%8==0, bijective): l2 = (lin%8)*24 + lin/8
// -> each XCD gets 24 raster-contiguous tiles (2 full bm rows): A-panels
// XCD-local, B streamed coherently.
// ---------------------------------------------------------------------------
template <int P>
__device__ __forceinline__ void mfmaq(f32x4 (&acc)[8][4],
                                      const bf16x8 (&af)[2][2],
                                      const bf16x8 (&bfr)[4][2]) {
#pragma unroll
    for (int m2 = 0; m2 < 2; m2++)
#pragma unroll
        for (int nt = 0; nt < 4; nt++)
#pragma unroll
            for (int ks = 0; ks < 2; ks++)
                acc[2 * P + m2][nt] = __builtin_amdgcn_mfma_f32_16x16x32_bf16(
                    af[m2][ks], bfr[nt][ks], acc[2 * P + m2][nt], 0, 0, 0);
}

__global__ __launch_bounds__(512) void gemm_qkv(
    const unsigned short* __restrict__ A, const unsigned short* __restrict__ B,
    unsigned short* __restrict__ C, int M, int N, int K)
{
    __shared__ __align__(16) unsigned short As[2][256 * 64];
    __shared__ __align__(16) unsigned short Bs[2][256 * 64];

    const int tid = threadIdx.x;
    // T1 XCD swizzle: lin in dispatch order; same XCD -> contiguous tiles.
    const int lin = (int)blockIdx.y * (int)gridDim.x + (int)blockIdx.x;  // 0..191
    const int l2 = (lin & 7) * 24 + (lin >> 3);                          // bijective
    const int bn = l2 % 12, bm = l2 / 12;
    const int w = tid >> 6, lane = tid & 63;
    const int quad = lane >> 4, l16 = lane & 15;
    const int wm = (w >> 2) * 128, wn = (w & 3) * 64;
    const int NT = K >> 6;                      // 16 K-tiles

    f32x4 acc[8][4] = {};

    const int srow8 = lane >> 3;                // 0..7 within 8-row group
    const int scol = ((lane & 7) ^ srow8) * 8;  // inverse-swizzled source col
    const unsigned short* Ab = A + (size_t)bm * 256 * K;
    const unsigned short* Bb = B + (size_t)bn * 256 * K;

    auto stage = [&](const unsigned short* __restrict__ G, unsigned short* lds,
                     int tT, int hh) {
#pragma unroll
        for (int i = 0; i < 2; i++) {
            const int r = hh * 128 + w * 16 + i * 8;      // wave-uniform
            gl2lds16(G + (size_t)(r + srow8) * K + tT * 64 + scol, lds + r * 64);
        }
    };
    auto ldA = [&](bf16x8 (&af)[2][2], const unsigned short* AsB, int p) {
#pragma unroll
        for (int m2 = 0; m2 < 2; m2++)
#pragma unroll
            for (int ks = 0; ks < 2; ks++)
                af[m2][ks] = *(const bf16x8*)swz(AsB, wm + p * 32 + m2 * 16 + l16,
                                                 ks * 32 + quad * 8);
    };
    auto ldB = [&](bf16x8 (&bf_)[4][2], const unsigned short* BsB) {
#pragma unroll
        for (int nt = 0; nt < 4; nt++)
#pragma unroll
            for (int ks = 0; ks < 2; ks++)
                bf_[nt][ks] = *(const bf16x8*)swz(BsB, wn + nt * 16 + l16,
                                                  ks * 32 + quad * 8);
    };

    // ---- prologue: B(0), A(0), B(1); wait tile-0 resident (B(1) in flight) ----
    stage(Bb, Bs[0], 0, 0); stage(Bb, Bs[0], 0, 1);
    stage(Ab, As[0], 0, 0); stage(Ab, As[0], 0, 1);
    stage(Bb, Bs[1], 1, 0); stage(Bb, Bs[1], 1, 1);
    asm volatile("s_waitcnt vmcnt(4)" ::: "memory");
    __builtin_amdgcn_s_barrier();

    for (int t = 0; t < NT; t++) {
        const unsigned short* AsB = As[t & 1];
        const unsigned short* BsB = Bs[t & 1];
        unsigned short* AsN = As[(t + 1) & 1];
        unsigned short* BsN = Bs[t & 1];        // (t+2)&1 == t&1
        bf16x8 bfr[4][2];
        // ---- phase 0: 12 ds_reads (A q0 + all B), stage A0(t+1) ----
        {
            bf16x8 af[2][2];
            ldA(af, AsB, 0);
            ldB(bfr, BsB);
            if (t + 1 < NT) stage(Ab, AsN, t + 1, 0);
            __builtin_amdgcn_s_barrier();
            asm volatile("s_waitcnt lgkmcnt(0)" ::: "memory");
            __builtin_amdgcn_sched_barrier(0);
            mfmaq<0>(acc, af, bfr);
            __builtin_amdgcn_s_barrier();
        }
        // ---- phase 1: A q1, stage A1(t+1) + B0(t+2) ----
        {
            bf16x8 af[2][2];
            ldA(af, AsB, 1);
            if (t + 1 < NT) stage(Ab, AsN, t + 1, 1);
            if (t + 2 < NT) stage(Bb, BsN, t + 2, 0);
            __builtin_amdgcn_s_barrier();
            asm volatile("s_waitcnt lgkmcnt(0)" ::: "memory");
            __builtin_amdgcn_sched_barrier(0);
            mfmaq<1>(acc, af, bfr);
            __builtin_amdgcn_s_barrier();
        }
        // ---- phase 2: A q2, stage B1(t+2) ----
        {
            bf16x8 af[2][2];
            ldA(af, AsB, 2);
            if (t + 2 < NT) stage(Bb, BsN, t + 2, 1);
            __builtin_amdgcn_s_barrier();
            asm volatile("s_waitcnt lgkmcnt(0)" ::: "memory");
            __builtin_amdgcn_sched_barrier(0);
            mfmaq<2>(acc, af, bfr);
            __builtin_amdgcn_s_barrier();
        }
        // ---- phase 3: A q3, counted vmcnt for next tile ----
        {
            bf16x8 af[2][2];
            ldA(af, AsB, 3);
            if (t < NT - 2)       asm volatile("s_waitcnt vmcnt(4)" ::: "memory");
            else if (t == NT - 2) asm volatile("s_waitcnt vmcnt(0)" ::: "memory");
            __builtin_amdgcn_s_barrier();
            asm volatile("s_waitcnt lgkmcnt(0)" ::: "memory");
            __builtin_amdgcn_sched_barrier(0);
            mfmaq<3>(acc, af, bfr);
            __builtin_amdgcn_s_barrier();
        }
    }

    // ---- epilogue: C bf16 ----
#pragma unroll
    for (int mf = 0; mf < 8; mf++) {
        const int row = bm * 256 + wm + mf * 16 + quad * 4;
#pragma unroll
        for (int nt = 0; nt < 4; nt++) {
            const int col = bn * 256 + wn + nt * 16 + l16;
#pragma unroll
            for (int r = 0; r < 4; r++)
                C[(size_t)(row + r) * N + col] = f2bf(acc[mf][nt][r]);
        }
    }
}

// ---------------------------------------------------------------------------
// gemm_proj v2: 64x128 tile (2/CU), BK=64 swizzled.  R8: non-attn best
// (124 us vs 128.6-133) — KEEP.
// ---------------------------------------------------------------------------
__global__ __launch_bounds__(256) void gemm_proj(
    const unsigned short* __restrict__ A, const unsigned short* __restrict__ B,
    const float* __restrict__ bias, float* __restrict__ C, int M, int N, int K)
{
    __shared__ __align__(16) unsigned short As[64 * 64];
    __shared__ __align__(16) unsigned short Bs[128 * 64];

    const int tid = threadIdx.x;
    const int bn = blockIdx.x, bm = blockIdx.y;   // bn 0..7, bm 0..63
    const int w = tid >> 6, lane = tid & 63;
    const int quad = lane >> 4, l16 = lane & 15;
    const int wm = (w >> 1) * 32, wn = (w & 1) * 64;   // wave tile 32x64

    f32x4 acc[2][4] = {};

    const int srow8 = lane >> 3;                // 0..7 within 8-row group
    const int scol = ((lane & 7) ^ srow8) * 8;  // inverse-swizzled source col
    const unsigned short* Ag = &A[(size_t)(bm * 64 + w * 16 + srow8) * K + scol];
    const unsigned short* Bg = &B[(size_t)(bn * 128 + w * 32 + srow8) * K + scol];
    unsigned short* AsW = &As[(w * 16) * 64];
    unsigned short* BsW = &Bs[(w * 32) * 64];

    for (int k0 = 0; k0 < K; k0 += 64) {
#pragma unroll
        for (int i = 0; i < 2; i++)
            gl2lds16(Ag + (size_t)(i * 8) * K + k0, AsW + i * 8 * 64);
#pragma unroll
        for (int i = 0; i < 4; i++)
            gl2lds16(Bg + (size_t)(i * 8) * K + k0, BsW + i * 8 * 64);
        __syncthreads();

#pragma unroll
        for (int ks = 0; ks < 2; ks++) {
            bf16x8 af[2], bfr[4];
#pragma unroll
            for (int t = 0; t < 2; t++)
                af[t]  = *(const bf16x8*)swz(As, wm + t * 16 + l16, ks * 32 + quad * 8);
#pragma unroll
            for (int t = 0; t < 4; t++)
                bfr[t] = *(const bf16x8*)swz(Bs, wn + t * 16 + l16, ks * 32 + quad * 8);
#pragma unroll
            for (int mt = 0; mt < 2; mt++)
#pragma unroll
                for (int nt = 0; nt < 4; nt++)
                    acc[mt][nt] = __builtin_amdgcn_mfma_f32_16x16x32_bf16(
                        af[mt], bfr[nt], acc[mt][nt], 0, 0, 0);
        }
        __syncthreads();
    }

#pragma unroll
    for (int mt = 0; mt < 2; mt++) {
        const int row = bm * 64 + wm + mt * 16 + quad * 4;
#pragma unroll
        for (int nt = 0; nt < 4; nt++) {
            const int col = bn * 128 + wn + nt * 16 + l16;
            const float bv = bias[col];
#pragma unroll
            for (int r = 0; r < 4; r++)
                C[(size_t)(row + r) * N + col] = acc[mt][nt][r] + bv;
        }
    }
}

// ---------------------------------------------------------------------------
// Fused causal flash attention — R4/R7-EXACT revert (measured 50.2-51.5 us
// three times).  R8 lesson: stripping VALU (pre-scaled Q, pointer increments)
// REGRESSED to 56.3 us — that VALU was free ILP filling latency slots between
// the barrier-ordered DS/MFMA chains (VALUBusy 57.8->48.6 and dur UP).
// Structure is a measured local optimum: barriers (R6), occupancy (R2/R3),
// setprio (R2), tile size (R5), VALU count (R8) all regressed.  DO NOT TOUCH.
// ---------------------------------------------------------------------------
__global__ __launch_bounds__(256) void attn_fused(
    const unsigned short* __restrict__ kqv,
    unsigned short* __restrict__ out)
{
    __shared__ __align__(16) unsigned short Qs[64 * 64];
    __shared__ __align__(16) unsigned short Ks[2][64 * 64];
    __shared__ __align__(16) unsigned short Vts[2][64 * 64];
    __shared__ __align__(16) unsigned short Ps[64 * 64];

    const int bh = blockIdx.x;                 // 0..31  (bh%8 = XCD)
    const int qt = 31 - (int)blockIdx.y;       // heavy tiles first
    const int b = bh >> 4, h = bh & 15;
    const int tid = threadIdx.x;
    const int w = tid >> 6;                    // wave 0..3
    const int lane = tid & 63;
    const int quad = lane >> 4, l16 = lane & 15;
    const int rowBase = b * 2048;
    const int kOff = h * 64, qOff = 1024 + h * 64, vOff = 2048 + h * 64;
    const float SEXP = 0.125f * 1.4426950408889634f;   // D^-0.5 folded into exp2
    const float MASKV = -1.0e30f;

    // ---- stage Q (swizzled) ----
#pragma unroll
    for (int i = 0; i < 2; i++) {
        const int v = tid + i * 256;
        const int row = v >> 3, c8 = (v & 7) * 8;
        *(u16x8*)swz(Qs, row, c8) =
            *(const u16x8*)&kqv[(size_t)(rowBase + qt * 64 + row) * 3072 + qOff + c8];
    }

    f32x4 o[4] = {};
    float l_i[4] = {0.f, 0.f, 0.f, 0.f};

    // ---- register prefetch of tile j=0 ----
    u16x8 kr[2], vr[2];
#pragma unroll
    for (int i = 0; i < 2; i++) {
        const int v = tid + i * 256;
        kr[i] = *(const u16x8*)&kqv[(size_t)(rowBase + (v >> 3)) * 3072 + kOff + (v & 7) * 8];
        vr[i] = *(const u16x8*)&kqv[(size_t)(rowBase + lane) * 3072 + vOff + (i * 4 + w) * 8];
    }

    for (int j = 0; j <= qt; j++) {
        const int cur = j & 1;
        // ---- regs -> LDS[cur] (K row-major; V transposed, kv=lane) ----
#pragma unroll
        for (int i = 0; i < 2; i++) {
            const int v = tid + i * 256;
            *(u16x8*)swz(Ks[cur], v >> 3, (v & 7) * 8) = kr[i];
            const int d8 = i * 4 + w;
#pragma unroll
            for (int u = 0; u < 8; u++)        // row&7 == u -> XOR is unroll-const
                *swz(Vts[cur], d8 * 8 + u, lane) = vr[i][u];
        }
        __syncthreads();   // Btop: tile j (and Qs at j=0) visible; prior-buffer
                           // reads AND prior-iter Ps reads drained

        // ---- prefetch tile j+1 into registers ----
        if (j < qt) {
#pragma unroll
            for (int i = 0; i < 2; i++) {
                const int v = tid + i * 256;
                kr[i] = *(const u16x8*)&kqv[(size_t)(rowBase + (j + 1) * 64 + (v >> 3)) * 3072 + kOff + (v & 7) * 8];
                vr[i] = *(const u16x8*)&kqv[(size_t)(rowBase + (j + 1) * 64 + lane) * 3072 + vOff + (i * 4 + w) * 8];
            }
        }

        // ---- S = Q K^T ----
        f32x4 s[4] = {};
#pragma unroll
        for (int ks = 0; ks < 2; ks++) {
            const bf16x8 aq = *(const bf16x8*)swz(Qs, w * 16 + l16, ks * 32 + quad * 8);
#pragma unroll
            for (int nt = 0; nt < 4; nt++) {
                const bf16x8 bk = *(const bf16x8*)swz(Ks[cur], nt * 16 + l16, ks * 32 + quad * 8);
                s[nt] = __builtin_amdgcn_mfma_f32_16x16x32_bf16(aq, bk, s[nt], 0, 0, 0);
            }
        }

        if (j == qt) {                 // diagonal tile: mask col > row
            const int rowl = w * 16 + quad * 4;
#pragma unroll
            for (int nt = 0; nt < 4; nt++) {
                const int coll = nt * 16 + l16;
#pragma unroll
                for (int r = 0; r < 4; r++)
                    if (coll > rowl + r) s[nt][r] = MASKV;
            }
        }

        // ---- P = exp2(S*c); l += P; store P (single buffer) ----
#pragma unroll
        for (int nt = 0; nt < 4; nt++) {
#pragma unroll
            for (int r = 0; r < 4; r++) {
                const float p = exp2f(s[nt][r] * SEXP);
                l_i[r] += p;
                *swz(Ps, w * 16 + quad * 4 + r, nt * 16 + l16) = f2bf(p);
            }
        }
        __syncthreads();   // B2: P visible (R6: removing this costs ~3 us)

        // ---- O += P @ V ----
#pragma unroll
        for (int ks = 0; ks < 2; ks++) {
            const bf16x8 ap = *(const bf16x8*)swz(Ps, w * 16 + l16, ks * 32 + quad * 8);
#pragma unroll
            for (int nt = 0; nt < 4; nt++) {
                const bf16x8 bv = *(const bf16x8*)swz(Vts[cur], nt * 16 + l16, ks * 32 + quad * 8);
                o[nt] = __builtin_amdgcn_mfma_f32_16x16x32_bf16(ap, bv, o[nt], 0, 0, 0);
            }
        }
        // no trailing barrier: next iter stages the OTHER K/V buffer; its Btop
        // orders those writes (and the next Ps write) after this iter's reads.
    }

    // ---- one cross-lane l reduction per q-tile ----
    float linv[4];
#pragma unroll
    for (int r = 0; r < 4; r++) {
        float t = l_i[r];
        t += __shfl_xor(t, 1);
        t += __shfl_xor(t, 2);
        t += __shfl_xor(t, 4);
        t += __shfl_xor(t, 8);
        linv[r] = 1.0f / t;
    }

    // ---- epilogue: O * (1/l) -> bf16 attn [B,T,H*D] ----
#pragma unroll
    for (int nt = 0; nt < 4; nt++) {
        const int col = h * 64 + nt * 16 + l16;
#pragma unroll
        for (int r = 0; r < 4; r++)
            out[(size_t)(rowBase + qt * 64 + w * 16 + quad * 4 + r) * 1024 + col] =
                f2bf(o[nt][r] * linv[r]);
    }
}

// ---------------------------------------------------------------------------
extern "C" void kernel_launch(void* const* d_in, const int* in_sizes, int n_in,
                              void* d_out, int out_size, void* d_ws, size_t ws_size,
                              hipStream_t stream) {
    const float* x     = (const float*)d_in[0];   // [4096][1024]
    const float* Wkqv  = (const float*)d_in[1];   // [3072][1024]
    const float* Wproj = (const float*)d_in[2];   // [1024][1024]
    const float* bproj = (const float*)d_in[3];   // [1024]
    float* out = (float*)d_out;                   // FP32

    unsigned short* kqv    = (unsigned short*)d_ws;
    unsigned short* attn   = kqv    + (size_t)4096 * 3072;
    unsigned short* xb     = attn   + (size_t)4096 * 1024;
    unsigned short* wkqvb  = xb     + (size_t)4096 * 1024;
    unsigned short* wprojb = wkqvb  + (size_t)3072 * 1024;

    cvt_bf16_3<<<dim3(512), dim3(256), 0, stream>>>(
        x, xb, 4096 * 1024, Wkqv, wkqvb, 3072 * 1024, Wproj, wprojb, 1024 * 1024);

    gemm_qkv<<<dim3(12, 16), dim3(512), 0, stream>>>(
        xb, wkqvb, kqv, 4096, 3072, 1024);

    attn_fused<<<dim3(32, 32), dim3(256), 0, stream>>>(kqv, attn);

    gemm_proj<<<dim3(8, 64), dim3(256), 0, stream>>>(
        attn, wprojb, bproj, out, 4096, 1024, 1024);
}